// Round 3
// baseline (350.157 us; speedup 1.0000x reference)
//
#include <hip/hip_runtime.h>

// Monarch block-diag: out[b, s*64+l] = sum_r w2[l,s,r] * sum_p x[b, r*64+p] * w1[r,l,p]
// B=8192, N=4096, blocks 64. fp32 in/out; bf16 MFMA compute.
//
// Prologue kernel: w1,w2 fp32 -> bf16 into d_ws (1 MiB).
// Main kernel: 512 thr (8 waves), b-tile 16, grid 512.
//   - x fp32 read ONCE, converted to persistent bf16 A-frags in registers (qc-invariant).
//   - q-chunks processed in PAIRS (qp = 2 chunks of 16 q each): stage-1 -> Y bf16 LDS,
//     stage-2 -> registers, for qi=0,1; then an epilogue writes BOTH chunks at once so
//     each global-store instruction covers a FULL 128-B L2 line (out[b][s*64+qp*32..+32]).
//   - R3 change: PLAIN stores (no nontemporal). Evidence across rounds 0-2: nt stores
//     defeated L2 write-combining (WRITE_SIZE = 2.0-2.1x ideal even with full-line
//     single-instruction stores, plus 33-49 MB of merge-fetches). Plain stores let L2
//     write-combine the fully-dirtied lines -> each 128-B line evicted exactly once.
//   - O epilogue buffer [16b][32 s-slot][32 l] fp32 = 64 KiB aliases Y (dead by then);
//     XOR swizzle phys4 = ((qi<<2)|lg)^(m&7) gives exactly 8 dwords/bank on write and
//     read phases (b128 minimum, conflict-free).

typedef __bf16 bf16x8 __attribute__((ext_vector_type(8)));
typedef float  float4v __attribute__((ext_vector_type(4)));

__global__ __launch_bounds__(256)
void cvt_weights(const float* __restrict__ w1, const float* __restrict__ w2,
                 __bf16* __restrict__ wb) {
    const int i = (blockIdx.x * 256 + threadIdx.x) * 8;  // grid 128 -> i < 262144
    float4v a = *(const float4v*)(w1 + i);
    float4v b = *(const float4v*)(w1 + i + 4);
    bf16x8 v;
    v[0]=(__bf16)a[0]; v[1]=(__bf16)a[1]; v[2]=(__bf16)a[2]; v[3]=(__bf16)a[3];
    v[4]=(__bf16)b[0]; v[5]=(__bf16)b[1]; v[6]=(__bf16)b[2]; v[7]=(__bf16)b[3];
    *(bf16x8*)(wb + i) = v;
    a = *(const float4v*)(w2 + i);
    b = *(const float4v*)(w2 + i + 4);
    v[0]=(__bf16)a[0]; v[1]=(__bf16)a[1]; v[2]=(__bf16)a[2]; v[3]=(__bf16)a[3];
    v[4]=(__bf16)b[0]; v[5]=(__bf16)b[1]; v[6]=(__bf16)b[2]; v[7]=(__bf16)b[3];
    *(bf16x8*)(wb + 262144 + i) = v;
}

__global__ __launch_bounds__(512, 4)
void monarch_fused(const float* __restrict__ x,
                   const __bf16* __restrict__ w1b,
                   const __bf16* __restrict__ w2b,
                   float* __restrict__ out)
{
    // smem union:
    //   Y: [b(16)][q(16)][kchunk(8) xor-swizzled][elem(8)] bf16 = 32 KiB (first half)
    //   O: [b(16)][slot(32)][phys-lp(32) xor-swizzled] fp32 = 64 KiB (whole buffer;
    //      only live AFTER stage-2 reads of Y complete, so aliasing is safe)
    __shared__ __align__(16) unsigned char smem[65536];
    __bf16* Y = (__bf16*)smem;
    float*  O = (float*)smem;

    const int tid  = threadIdx.x;
    const int wid  = tid >> 6;      // 0..7
    const int lane = tid & 63;
    const int m    = lane & 15;     // MFMA: A-M / B-N / D-col index
    const int quad = lane >> 4;     // MFMA: A/B K-group, D row-group
    const int b0   = blockIdx.x * 16;

    // ---- preload x as bf16 A-frags: k = wid*8 + j, kk = h*32 + quad*8 + e ----
    bf16x8 xa[8][2];
    {
        const float* xp = x + (long)(b0 + m) * 4096 + wid * 512 + quad * 8;
        #pragma unroll
        for (int j = 0; j < 8; ++j) {
            #pragma unroll
            for (int h = 0; h < 2; ++h) {
                float4v lo = *(const float4v*)(xp + j * 64 + h * 32);
                float4v hi = *(const float4v*)(xp + j * 64 + h * 32 + 4);
                bf16x8 v;
                v[0]=(__bf16)lo[0]; v[1]=(__bf16)lo[1]; v[2]=(__bf16)lo[2]; v[3]=(__bf16)lo[3];
                v[4]=(__bf16)hi[0]; v[5]=(__bf16)hi[1]; v[6]=(__bf16)hi[2]; v[7]=(__bf16)hi[3];
                xa[j][h] = v;
            }
        }
    }

    const int lg = wid >> 1;  // l-group (4 l each)
    const int sh = wid & 1;   // s-half (2 s-tiles each)

    for (int qp = 0; qp < 2; ++qp) {
        float4v acc2[2][4][2];  // [qi][li][st]

        #pragma unroll
        for (int qi = 0; qi < 2; ++qi) {
            const int qc = qp * 2 + qi;

            // ---- stage 1: Y[b][q in chunk][k] ; wave handles k in [wid*8, wid*8+8) ----
            float4v acc[8];
            #pragma unroll
            for (int j = 0; j < 8; ++j) {
                const int k = wid * 8 + j;
                const __bf16* w1p = w1b + ((k * 64 + qc * 16 + m) * 64) + quad * 8;
                bf16x8 bb0 = *(const bf16x8*)(w1p);
                bf16x8 bb1 = *(const bf16x8*)(w1p + 32);
                float4v c = {0.f, 0.f, 0.f, 0.f};
                c = __builtin_amdgcn_mfma_f32_16x16x32_bf16(xa[j][0], bb0, c, 0, 0, 0);
                c = __builtin_amdgcn_mfma_f32_16x16x32_bf16(xa[j][1], bb1, c, 0, 0, 0);
                acc[j] = c;
            }

            __syncthreads();  // previous LDS consumers done (stage-2 Y reads / O reads)

            // D: lane holds D[b = quad*4+reg][q = qc*16+m], value acc[j][reg] for k=wid*8+j.
            #pragma unroll
            for (int reg = 0; reg < 4; ++reg) {
                const int bl = quad * 4 + reg;
                const int cs = wid ^ (m & 7) ^ (bl & 7);
                bf16x8 v;
                #pragma unroll
                for (int j = 0; j < 8; ++j) v[j] = (__bf16)acc[j][reg];
                *(bf16x8*)(&Y[((bl * 16 + m) * 8 + cs) * 8]) = v;
            }
            __syncthreads();

            // ---- stage 2: l = qc*16 + lg*4 + li ; s-tiles sh*2+st -> acc2[qi] ----
            #pragma unroll
            for (int li = 0; li < 4; ++li)
                #pragma unroll
                for (int st = 0; st < 2; ++st) acc2[qi][li][st] = (float4v){0.f, 0.f, 0.f, 0.f};

            #pragma unroll
            for (int h = 0; h < 2; ++h) {
                #pragma unroll
                for (int li = 0; li < 4; ++li) {
                    const int ll = lg * 4 + li;
                    const int l  = qc * 16 + ll;
                    const int kc = h * 4 + quad;
                    const int cs = kc ^ (ll & 7) ^ (m & 7);
                    // A2[b = m][r = h*32 + quad*8 + e] = Y[b][ll][r]
                    bf16x8 a2 = *(const bf16x8*)(&Y[((m * 16 + ll) * 8 + cs) * 8]);
                    const __bf16* w2p = w2b + (l * 64) * 64 + h * 32 + quad * 8;
                    #pragma unroll
                    for (int st = 0; st < 2; ++st) {
                        const int s = (sh * 2 + st) * 16 + m;
                        bf16x8 b2 = *(const bf16x8*)(w2p + s * 64);
                        acc2[qi][li][st] = __builtin_amdgcn_mfma_f32_16x16x32_bf16(a2, b2, acc2[qi][li][st], 0, 0, 0);
                    }
                }
            }
        }

        __syncthreads();  // all waves done reading Y before O overwrites it

        // ---- epilogue: 2 rounds (by st). Round st covers s in {sh*32 + st*16 + m}.
        // O dword addr = (bl*32 + slot)*32 + phys4*4 + li,
        //   slot = m + sh*16 (s = (sh*2+st)*16+m), phys4 = ((qi<<2)|lg) ^ (m&7).
        // Write phase: per instr, 8 lanes per 4-bank group -> 8 dwords/bank (minimal).
        // Read phase: 8 consecutive slots x lanef8 -> same 8 dwords/bank.
        #pragma unroll
        for (int st = 0; st < 2; ++st) {
            if (st) __syncthreads();  // round-0 O reads done before round-1 overwrites

            const int slot = m + sh * 16;
            #pragma unroll
            for (int qi = 0; qi < 2; ++qi) {
                const int p4 = ((qi << 2) | lg) ^ (m & 7);
                #pragma unroll
                for (int reg = 0; reg < 4; ++reg) {
                    const int bl = quad * 4 + reg;
                    float4v v;
                    #pragma unroll
                    for (int li = 0; li < 4; ++li) v[li] = acc2[qi][li][st][reg];
                    *(float4v*)(&O[(bl * 32 + slot) * 32 + p4 * 4]) = v;
                }
            }
            __syncthreads();

            // coalesced read + full-line global store: 8 phases x 512 thr x float4 = 64 KiB.
            // 8 adjacent lanes cover one contiguous 128-B chunk out[b][s*64+qp*32 .. +32]
            // -> every touched L2 line fully dirtied by ONE instruction; plain (temporal)
            // stores so L2 write-combines and evicts each line exactly once.
            #pragma unroll
            for (int ph = 0; ph < 8; ++ph) {
                const int g      = ph * 512 + tid;
                const int lanef8 = g & 7;
                const int c      = g >> 3;       // 0..511
                const int rslot  = c & 31;
                const int bl     = c >> 5;       // 0..15
                const int phys   = (lanef8 ^ (rslot & 7)) << 2;
                float4v v = *(const float4v*)(&O[(bl * 32 + rslot) * 32 + phys]);
                const int s = ((rslot >> 4) * 2 + st) * 16 + (rslot & 15);
                float* dst = out + (long)(b0 + bl) * 4096 + s * 64 + qp * 32 + lanef8 * 4;
                *(float4v*)dst = v;
            }
        }
        // next qp's first __syncthreads protects this round's O reads
    }
}

extern "C" void kernel_launch(void* const* d_in, const int* in_sizes, int n_in,
                              void* d_out, int out_size, void* d_ws, size_t ws_size,
                              hipStream_t stream) {
    const float* x  = (const float*)d_in[0];
    const float* w1 = (const float*)d_in[1];
    const float* w2 = (const float*)d_in[2];
    float* out = (float*)d_out;
    __bf16* wb = (__bf16*)d_ws;   // w1b at [0, 262144), w2b at [262144, 524288)

    hipLaunchKernelGGL(cvt_weights, dim3(128), dim3(256), 0, stream, w1, w2, wb);
    hipLaunchKernelGGL(monarch_fused, dim3(8192 / 16), dim3(512), 0, stream,
                       x, wb, wb + 262144, out);
}

// Round 4
// 300.033 us; speedup vs baseline: 1.1671x; 1.1671x over previous
//
#include <hip/hip_runtime.h>

// Monarch block-diag: out[b, s*64+l] = sum_r w2[l,s,r] * sum_p x[b, r*64+p] * w1[r,l,p]
// B=8192, N=4096, blocks 64. fp32 in/out; bf16 MFMA compute.
//
// R4 structure (full-Y): evidence r0-r3 shows WRITE amplification (exactly 2.125x, invariant
// to store flavor & instruction-level line coverage) comes from TEMPORAL splitting of 256-B
// out granules across q-chunks at the L3/HBM level. Every 256-B out region spans all 64 l
// (= all q), so the fix is structural: hold the FULL Y tile (16b x 64l x 64r bf16 = 128 KiB
// LDS) per block, compute all of stage-2 into registers, then store each 256-B out run
// [b][s*64..+64] contiguously by 16 adjacent lanes in one temporal window.
//
// Main kernel: 1024 thr (16 waves), b-tile 16, grid 512, 128 KiB dynamic LDS, 5 barriers.
//   stage-1: waves = (kw 0..7) x (qh 0..1); x bf16 A-frags in regs (read once, coalesced);
//            w1 from L2; Y[b][q(64)][kchunk(8) xor-swz][8] bf16 writes (8 dw/bank minimal).
//   stage-2: waves = (lgrp 0..3) x (sgrp 0..3); acc2[16] f32x4 = 16b x 16s per wave over
//            16 l; A2 from Y (swz reads, 8 dw/bank), B2 = w2 from L2.
//   epilogue: O[b(16)][so(32)][l(64)] f32 = 128 KiB aliases dead Y; 2 rounds by s-half;
//            O-atom swizzle phys = l4 ^ (so&7) ^ (quad<<1) -> 8 dw/bank both phases;
//            stores: 16 lanes = one aligned 256-B run, all l at once (plain stores).

typedef __bf16 bf16x8 __attribute__((ext_vector_type(8)));
typedef float  float4v __attribute__((ext_vector_type(4)));

__global__ __launch_bounds__(256)
void cvt_weights(const float* __restrict__ w1, const float* __restrict__ w2,
                 __bf16* __restrict__ wb) {
    const int i = (blockIdx.x * 256 + threadIdx.x) * 8;  // grid 128 -> i < 262144
    float4v a = *(const float4v*)(w1 + i);
    float4v b = *(const float4v*)(w1 + i + 4);
    bf16x8 v;
    v[0]=(__bf16)a[0]; v[1]=(__bf16)a[1]; v[2]=(__bf16)a[2]; v[3]=(__bf16)a[3];
    v[4]=(__bf16)b[0]; v[5]=(__bf16)b[1]; v[6]=(__bf16)b[2]; v[7]=(__bf16)b[3];
    *(bf16x8*)(wb + i) = v;
    a = *(const float4v*)(w2 + i);
    b = *(const float4v*)(w2 + i + 4);
    v[0]=(__bf16)a[0]; v[1]=(__bf16)a[1]; v[2]=(__bf16)a[2]; v[3]=(__bf16)a[3];
    v[4]=(__bf16)b[0]; v[5]=(__bf16)b[1]; v[6]=(__bf16)b[2]; v[7]=(__bf16)b[3];
    *(bf16x8*)(wb + 262144 + i) = v;
}

__global__ __launch_bounds__(1024, 4)
void monarch_fused(const float* __restrict__ x,
                   const __bf16* __restrict__ w1b,
                   const __bf16* __restrict__ w2b,
                   float* __restrict__ out)
{
    // 128 KiB dynamic LDS:
    //   Y: [b(16)][q(64)][kchunk(8) xor-swz][elem(8)] bf16 = 128 KiB
    //   O: [b(16)][so(32)][l(64) atom-swz] fp32 = 128 KiB (aliases Y after stage-2)
    extern __shared__ __align__(16) unsigned char smem[];
    __bf16* Y = (__bf16*)smem;
    float*  O = (float*)smem;

    const int tid  = threadIdx.x;
    const int wid  = tid >> 6;      // 0..15
    const int lane = tid & 63;
    const int m    = lane & 15;     // MFMA: A-M / B-N / D-col index
    const int quad = lane >> 4;     // MFMA: A/B K-group, D row-group
    const int b0   = blockIdx.x * 16;

    // ---- stage-1 wave roles ----
    const int kw = wid & 7;   // k-chunk of 8
    const int qh = wid >> 3;  // q-half (2 q-tiles of 16)

    // ---- preload x as bf16 A-frags: k = kw*8 + j, kk = h*32 + quad*8 + e ----
    bf16x8 xa[8][2];
    {
        const float* xp = x + (long)(b0 + m) * 4096 + kw * 512 + quad * 8;
        #pragma unroll
        for (int j = 0; j < 8; ++j) {
            #pragma unroll
            for (int h = 0; h < 2; ++h) {
                float4v lo = *(const float4v*)(xp + j * 64 + h * 32);
                float4v hi = *(const float4v*)(xp + j * 64 + h * 32 + 4);
                bf16x8 v;
                v[0]=(__bf16)lo[0]; v[1]=(__bf16)lo[1]; v[2]=(__bf16)lo[2]; v[3]=(__bf16)lo[3];
                v[4]=(__bf16)hi[0]; v[5]=(__bf16)hi[1]; v[6]=(__bf16)hi[2]; v[7]=(__bf16)hi[3];
                xa[j][h] = v;
            }
        }
    }

    // ---- stage 1: Y[b][q][k] for k in [kw*8, kw*8+8), q in [qh*32, qh*32+32) ----
    #pragma unroll
    for (int t = 0; t < 2; ++t) {
        const int qt = qh * 2 + t;
        float4v acc[8];
        #pragma unroll
        for (int j = 0; j < 8; ++j) {
            const int k = kw * 8 + j;
            const __bf16* w1p = w1b + ((k * 64 + qt * 16 + m) * 64) + quad * 8;
            bf16x8 bb0 = *(const bf16x8*)(w1p);
            bf16x8 bb1 = *(const bf16x8*)(w1p + 32);
            float4v c = {0.f, 0.f, 0.f, 0.f};
            c = __builtin_amdgcn_mfma_f32_16x16x32_bf16(xa[j][0], bb0, c, 0, 0, 0);
            c = __builtin_amdgcn_mfma_f32_16x16x32_bf16(xa[j][1], bb1, c, 0, 0, 0);
            acc[j] = c;
        }
        // D: lane holds D[b = quad*4+reg][q = qt*16+m], value acc[j][reg] for k = kw*8+j.
        #pragma unroll
        for (int reg = 0; reg < 4; ++reg) {
            const int bl = quad * 4 + reg;
            const int q  = qt * 16 + m;
            const int cs = kw ^ (m & 7) ^ (bl & 7);
            bf16x8 v;
            #pragma unroll
            for (int j = 0; j < 8; ++j) v[j] = (__bf16)acc[j][reg];
            *(bf16x8*)(&Y[((bl * 64 + q) * 8 + cs) * 8]) = v;
        }
    }
    __syncthreads();

    // ---- stage 2: wave = (lgrp, sgrp); l in [lgrp*16,+16), s = sgrp*16 + m ----
    const int lgrp = wid & 3;
    const int sgrp = wid >> 2;
    const int s    = sgrp * 16 + m;

    float4v acc2[16];
    #pragma unroll
    for (int li = 0; li < 16; ++li) acc2[li] = (float4v){0.f, 0.f, 0.f, 0.f};

    #pragma unroll
    for (int h = 0; h < 2; ++h) {
        #pragma unroll
        for (int li = 0; li < 16; ++li) {
            const int l   = lgrp * 16 + li;
            const int cs2 = (h * 4 + quad) ^ (l & 7) ^ (m & 7);
            // A2[b = m][r = h*32 + quad*8 + e] = Y[b][l][r]
            bf16x8 a2 = *(const bf16x8*)(&Y[((m * 64 + l) * 8 + cs2) * 8]);
            bf16x8 b2 = *(const bf16x8*)(w2b + l * 4096 + s * 64 + h * 32 + quad * 8);
            acc2[li] = __builtin_amdgcn_mfma_f32_16x16x32_bf16(a2, b2, acc2[li], 0, 0, 0);
        }
    }
    __syncthreads();  // all Y reads done; O may overwrite

    // ---- epilogue: 2 rounds by s-half h2; O[b][so(32)][l(64)] with 16-B atom swizzle
    // phys = l4 ^ (so&7) ^ (quad<<1)  (quad = b>>2) -> 8 dwords/bank on write AND read.
    #pragma unroll
    for (int h2 = 0; h2 < 2; ++h2) {
        if (h2) __syncthreads();  // round-0 O reads complete before round-1 overwrites

        if ((sgrp >> 1) == h2) {  // wave-uniform predicate: 8 writer waves per round
            const int so = (sgrp & 1) * 16 + m;   // s = h2*32 + so
            #pragma unroll
            for (int li4 = 0; li4 < 4; ++li4) {
                const int l4 = lgrp * 4 + li4;
                #pragma unroll
                for (int reg = 0; reg < 4; ++reg) {
                    const int b    = quad * 4 + reg;
                    const int phys = l4 ^ (so & 7) ^ (quad << 1);
                    float4v v = { acc2[li4 * 4 + 0][reg], acc2[li4 * 4 + 1][reg],
                                  acc2[li4 * 4 + 2][reg], acc2[li4 * 4 + 3][reg] };
                    *(float4v*)(&O[((b * 32 + so) << 6) + (phys << 2)]) = v;
                }
            }
        }
        __syncthreads();

        // read + store: 8 iters x 1024 thr x float4 = 128 KiB; 16 adjacent lanes cover one
        // contiguous aligned 256-B run out[b][s*64 .. +64] (all l at once) in one instr.
        const int l4r = tid & 15;
        const int sor = (tid >> 4) & 31;
        #pragma unroll
        for (int it = 0; it < 8; ++it) {
            const int b    = it * 2 + (tid >> 9);
            const int phys = l4r ^ (sor & 7) ^ (((b >> 2) & 3) << 1);
            float4v v = *(const float4v*)(&O[((b * 32 + sor) << 6) + (phys << 2)]);
            float* dst = out + (long)(b0 + b) * 4096 + (h2 * 32 + sor) * 64 + l4r * 4;
            *(float4v*)dst = v;
        }
    }
}

extern "C" void kernel_launch(void* const* d_in, const int* in_sizes, int n_in,
                              void* d_out, int out_size, void* d_ws, size_t ws_size,
                              hipStream_t stream) {
    const float* x  = (const float*)d_in[0];
    const float* w1 = (const float*)d_in[1];
    const float* w2 = (const float*)d_in[2];
    float* out = (float*)d_out;
    __bf16* wb = (__bf16*)d_ws;   // w1b at [0, 262144), w2b at [262144, 524288)

    hipLaunchKernelGGL(cvt_weights, dim3(128), dim3(256), 0, stream, w1, w2, wb);
    hipLaunchKernelGGL(monarch_fused, dim3(8192 / 16), dim3(1024), 131072, stream,
                       x, wb, wb + 262144, out);
}